// Round 13
// baseline (395.428 us; speedup 1.0000x reference)
//
#include <hip/hip_runtime.h>
#include <cstddef>

#define HH 720
#define WW 1280
#define FRAME 1843200            // 2*720*1280
#define FRAME4 460800            // FRAME/4
#define T_EVT 10
#define T_TOTAL 20
#define ARRIVE64 (1ULL << 32)

// ---------- old (fallback) path config ----------
#define ONBLK 256
#define ONTHR 1024
#define ONWPB 16
#define ONT (ONBLK * ONTHR)

// ---------- new path config ----------
#define SBLK 1024                // scan blocks (4 per CU)
#define STHR 256                 // scan threads per block (4 waves)
#define SWPB 4
#define PIXB 1800                // pixels per scan block
#define NGROUP4 450              // float4 groups per block (1800/4)
#define HIST_W 9000              // LDS hist words (18000 u16)
#define RBLK 512                 // passA/passB blocks (x1024 thr = 32 waves/CU)
#define RTHR 1024
#define OTHR 512                 // offsets kernel threads (one per mat row)
#define NBUCKET 1024

// ws layout (bytes), all 256-aligned
#define MAT_OFF   0u                           // u32[512*1024] = 2 MB
#define CS_OFF    (512u * 1024u * 4u)          // u32[1024] column sums
#define SB_OFF    (CS_OFF + 4096u)             // u32[1025] seg bases
#define KEY_OFF   (SB_OFF + 8192u)             // u32[n] pix keys
#define SEG_OFF(n) (KEY_OFF + 4u * (unsigned)(n))        // u16[n]
#define WS_NEED(n) ((size_t)SEG_OFF(n) + 2ull * (size_t)(n) + 256ull)

// Persistent device globals.
__device__ unsigned g_minkey;
__device__ unsigned g_maxkey;
__device__ unsigned g_done;                      // offsets arrival counter
// old-path tree (R8, proven)
__device__ unsigned long long g_grp[T_TOTAL][16][16];
__device__ unsigned long long g_top[T_TOTAL][16];
__device__ unsigned g_rel[T_TOTAL][32];
// new-path tree: 1024 -> 64 -> 4 -> 1, fan-out to 64 group-release words
__device__ unsigned long long g_n1[T_TOTAL][64][16];
__device__ unsigned long long g_n2[T_TOTAL][4][16];
__device__ unsigned long long g_n3[T_TOTAL][16];
__device__ unsigned g_relg[T_TOTAL][64][32];   // [s][group][0]: total+1

__device__ __forceinline__ unsigned f2key(float f) {
    unsigned b = __float_as_uint(f);
    return b ^ ((unsigned)(((int)b) >> 31) | 0x80000000u);
}
__device__ __forceinline__ float key2f(unsigned k) {
    unsigned b = (k & 0x80000000u) ? (k ^ 0x80000000u) : ~k;
    return __uint_as_float(b);
}

// Exact reference bin: ((t-tmin)/(tmax-tmin))*(10-1e-6), trunc, clip.
__device__ __forceinline__ int event_bin_t(float tv, float tmin, float tmax) {
#pragma clang fp contract(off)
    float tn;
    if (tmax > tmin) tn = (tv - tmin) / (tmax - tmin) * (float)(10.0 - 1e-6);
    else tn = 0.0f;
    int ti = (int)tn;
    return ti < 0 ? 0 : (ti > T_EVT - 1 ? T_EVT - 1 : ti);
}
__device__ __forceinline__ int event_pixel(int xi, int yi, int ci) {
    xi = xi < 0 ? 0 : (xi > WW - 1 ? WW - 1 : xi);
    yi = yi < 0 ? 0 : (yi > HH - 1 ? HH - 1 : yi);
    return ci * (HH * WW) + yi * WW + xi;
}

__global__ void init_kernel() {
    const int gtid = blockIdx.x * blockDim.x + threadIdx.x;
    const int gs = gridDim.x * blockDim.x;
    if (gtid == 0) { g_minkey = 0xFFFFFFFFu; g_maxkey = 0u; g_done = 0u; }
    unsigned long long* a = &g_grp[0][0][0];
    for (int i = gtid; i < T_TOTAL * 16 * 16; i += gs) a[i] = 0ull;
    unsigned long long* b = &g_top[0][0];
    for (int i = gtid; i < T_TOTAL * 16; i += gs) b[i] = 0ull;
    unsigned* c = &g_rel[0][0];
    for (int i = gtid; i < T_TOTAL * 32; i += gs) c[i] = 0u;
    unsigned long long* d = &g_n1[0][0][0];
    for (int i = gtid; i < T_TOTAL * 64 * 16; i += gs) d[i] = 0ull;
    unsigned long long* e = &g_n2[0][0][0];
    for (int i = gtid; i < T_TOTAL * 4 * 16; i += gs) e[i] = 0ull;
    unsigned long long* f = &g_n3[0][0];
    for (int i = gtid; i < T_TOTAL * 16; i += gs) f[i] = 0ull;
    unsigned* g = &g_relg[0][0][0];
    for (int i = gtid; i < T_TOTAL * 64 * 32; i += gs) g[i] = 0u;
}

// ======================= shared: t min/max =======================
__device__ __forceinline__ void minmax_body(const float* __restrict__ t, int n,
                                            int gtid, int gstride) {
    unsigned mn = 0xFFFFFFFFu, mx = 0u;
    const int n4 = n >> 2;
    const float4* t4 = (const float4*)t;
    for (int i = gtid; i < n4; i += gstride) {
        float4 tv = t4[i];
        unsigned k0 = f2key(tv.x), k1 = f2key(tv.y);
        unsigned k2 = f2key(tv.z), k3 = f2key(tv.w);
        unsigned a = k0 < k1 ? k0 : k1, b = k2 < k3 ? k2 : k3;
        unsigned c = a < b ? a : b;
        mn = mn < c ? mn : c;
        a = k0 > k1 ? k0 : k1; b = k2 > k3 ? k2 : k3;
        c = a > b ? a : b;
        mx = mx > c ? mx : c;
    }
    for (int i = (n4 << 2) + gtid; i < n; i += gstride) {
        unsigned k = f2key(t[i]);
        mn = mn < k ? mn : k;
        mx = mx > k ? mx : k;
    }
    for (int off = 32; off > 0; off >>= 1) {
        unsigned omn = (unsigned)__shfl_down((int)mn, off, 64);
        unsigned omx = (unsigned)__shfl_down((int)mx, off, 64);
        mn = mn < omn ? mn : omn;
        mx = mx > omx ? mx : omx;
    }
    __shared__ unsigned smn[16], smx[16];
    int lane = threadIdx.x & 63, wv = threadIdx.x >> 6;
    if (lane == 0) { smn[wv] = mn; smx[wv] = mx; }
    __syncthreads();
    if (threadIdx.x == 0) {
        int nw = blockDim.x >> 6;
        for (int i = 1; i < nw; ++i) {
            mn = mn < smn[i] ? mn : smn[i];
            mx = mx > smx[i] ? mx : smx[i];
        }
        atomicMin(&g_minkey, mn);
        atomicMax(&g_maxkey, mx);
    }
}

__global__ void minmax_zero_kernel(const float* __restrict__ t, int n,
                                   uint4* __restrict__ hist16v) {
    const int gtid = blockIdx.x * blockDim.x + threadIdx.x;
    const int gstride = gridDim.x * blockDim.x;
    const uint4 z = make_uint4(0u, 0u, 0u, 0u);
    const int nz = T_EVT * FRAME / 8;
    for (int i = gtid; i < nz; i += gstride) hist16v[i] = z;
    minmax_body(t, n, gtid, gstride);
}

// ======================= new path: counting sort =======================
// passA: events read ONCE -> pix keys (u32, 16 MB) + LDS bucket counts + t
// minmax. (ti can't go in the key: tmin/tmax unknown until this kernel ends;
// passB recomputes ti from a coalesced t read — 32 MB total passB input vs
// 64 MB raw re-decode, the R12 regression.)
__global__ __launch_bounds__(RTHR) void passA_kernel(
        const int* __restrict__ x, const int* __restrict__ y,
        const int* __restrict__ p, const float* __restrict__ t,
        unsigned* __restrict__ mat, unsigned* __restrict__ keys, int n) {
    __shared__ unsigned cnt[NBUCKET];
    for (int i = threadIdx.x; i < NBUCKET; i += blockDim.x) cnt[i] = 0u;
    __syncthreads();
    const int chunk = (n + (int)gridDim.x - 1) / (int)gridDim.x;
    const int s0 = blockIdx.x * chunk;
    const int s1 = min(n, s0 + chunk);
    for (int i = s0 + threadIdx.x; i < s1; i += blockDim.x) {
        int pix = event_pixel(x[i], y[i], p[i]);
        keys[i] = (unsigned)pix;
        atomicAdd(&cnt[pix / PIXB], 1u);
    }
    // minmax over t: global grid-stride, float4 (independent of chunking)
    minmax_body(t, n, blockIdx.x * blockDim.x + threadIdx.x,
                gridDim.x * blockDim.x);
    __syncthreads();
    for (int i = threadIdx.x; i < NBUCKET; i += blockDim.x)
        mat[blockIdx.x * NBUCKET + i] = cnt[i];
}

// Fused offsets (R12, proven): 1024 blocks do the 512-row column scans; the
// LAST-arriving block (release threadfence -> wbl2, agent arrival counter,
// agent-scope loads) does the 1024-wide top scan.
__global__ __launch_bounds__(OTHR) void offsets_kernel(
        unsigned* __restrict__ mat, unsigned* __restrict__ colsum,
        unsigned* __restrict__ seg_base) {
    const int j = blockIdx.x;        // bucket
    const int r = threadIdx.x;       // row (passA block), 0..511
    const int lane = r & 63, wv = r >> 6;
    __shared__ unsigned wtot[OTHR / 64];
    __shared__ unsigned last_flag;
    {
        unsigned v = mat[r * NBUCKET + j];
        unsigned incl = v;
        for (int off = 1; off < 64; off <<= 1) {
            unsigned o = (unsigned)__shfl_up((int)incl, off, 64);
            if (lane >= off) incl += o;
        }
        if (lane == 63) wtot[wv] = incl;
        __syncthreads();
        if (r == 0) {
            unsigned run = 0;
#pragma unroll
            for (int k = 0; k < OTHR / 64; ++k) { unsigned tmp = wtot[k]; wtot[k] = run; run += tmp; }
        }
        __syncthreads();
        unsigned ex = incl - v + wtot[wv];
        mat[r * NBUCKET + j] = ex;
        if (r == OTHR - 1) colsum[j] = ex + v;
    }
    __syncthreads();   // col stores drained (vmcnt) before arrival
    if (r == 0) {
        __threadfence();  // release: push this XCD's dirty L2 lines out
        unsigned old = __hip_atomic_fetch_add(&g_done, 1u, __ATOMIC_RELAXED,
                                              __HIP_MEMORY_SCOPE_AGENT);
        last_flag = (old == NBUCKET - 1) ? 1u : 0u;
    }
    __syncthreads();
    if (last_flag) {
        __shared__ unsigned sb[NBUCKET];
        __shared__ unsigned wt2[OTHR / 64];
        for (int i = r; i < NBUCKET; i += OTHR)
            sb[i] = __hip_atomic_load(&colsum[i], __ATOMIC_RELAXED,
                                      __HIP_MEMORY_SCOPE_AGENT);
        __syncthreads();
        unsigned a = sb[2 * r], bb = sb[2 * r + 1];
        unsigned s = a + bb;
        unsigned incl = s;
        for (int off = 1; off < 64; off <<= 1) {
            unsigned o = (unsigned)__shfl_up((int)incl, off, 64);
            if (lane >= off) incl += o;
        }
        if (lane == 63) wt2[wv] = incl;
        __syncthreads();
        if (r == 0) {
            unsigned run = 0;
#pragma unroll
            for (int k = 0; k < OTHR / 64; ++k) { unsigned tmp = wt2[k]; wt2[k] = run; run += tmp; }
        }
        __syncthreads();
        unsigned exs = incl - s + wt2[wv];
        seg_base[2 * r] = exs;
        seg_base[2 * r + 1] = exs + a;
        if (r == OTHR - 1) seg_base[NBUCKET] = exs + s;
    }
}

// passB: keys (16 MB) + t (16 MB) -> LDS rank -> u16 seg. Same chunking as
// passA so row offsets line up.
__global__ __launch_bounds__(RTHR) void passB_kernel(
        const unsigned* __restrict__ keys, const float* __restrict__ t,
        const unsigned* __restrict__ mat, const unsigned* __restrict__ seg_base,
        unsigned short* __restrict__ seg, int n) {
    __shared__ unsigned base[NBUCKET];
    for (int i = threadIdx.x; i < NBUCKET; i += blockDim.x)
        base[i] = mat[blockIdx.x * NBUCKET + i] + seg_base[i];
    __syncthreads();
    const float tmin = key2f(g_minkey);
    const float tmax = key2f(g_maxkey);
    const int chunk = (n + (int)gridDim.x - 1) / (int)gridDim.x;
    const int s0 = blockIdx.x * chunk;
    const int s1 = min(n, s0 + chunk);
    for (int i = s0 + threadIdx.x; i < s1; i += blockDim.x) {
        int pix = (int)keys[i];
        int ti = event_bin_t(t[i], tmin, tmax);
        int bkt = pix / PIXB;
        int lb = ti * PIXB + (pix - bkt * PIXB);   // < 18000
        unsigned idx = atomicAdd(&base[bkt], 1u);
        seg[idx] = (unsigned short)lb;
    }
}

// Cooperative scan, 1024 blocks x 256 thr, 36 KB LDS hist (R9-R12, proven).
__global__ __launch_bounds__(STHR, 4) void scan_new(float* __restrict__ out,
                                                    const unsigned short* __restrict__ seg,
                                                    const unsigned* __restrict__ seg_base) {
#pragma clang fp contract(off)
    const float decay = (float)0.9048374180359595;  // float32(exp(-1/10))
    const int tid = threadIdx.x;
    const int lane = tid & 63;
    const int b = blockIdx.x;
    const int pix0 = b * PIXB;

    __shared__ unsigned lds_hist[HIST_W];
    __shared__ unsigned lds_arr[T_TOTAL];
    __shared__ unsigned lds_tot[T_TOTAL];

    for (int i = tid; i < HIST_W; i += STHR) lds_hist[i] = 0u;
    if (tid < T_TOTAL) { lds_arr[tid] = 0u; lds_tot[tid] = 0u; }
    __syncthreads();

    {
        const int e0 = (int)seg_base[b];
        const int e1 = (int)seg_base[b + 1];
        for (int i = e0 + tid; i < e1; i += STHR) {
            unsigned lb = seg[i];
            atomicAdd(&lds_hist[lb >> 1], 1u << ((lb & 1u) << 4));
        }
    }
    __syncthreads();

    const bool has1 = tid < (NGROUP4 - STHR);
    float4 mem0 = make_float4(0.f, 0.f, 0.f, 0.f);
    float4 mem1 = make_float4(0.f, 0.f, 0.f, 0.f);
    float thr = 1.0f;

    for (int s = 0; s < T_TOTAL; ++s) {
        float* ob = out + (size_t)s * FRAME + pix0;
        int cnt = 0;

        {
            float4 f;
            if (s < T_EVT) {
                int w = s * 900 + (tid << 1);
                unsigned w0 = lds_hist[w], w1 = lds_hist[w + 1];
                f = make_float4((float)(w0 & 0xFFFFu), (float)(w0 >> 16),
                                (float)(w1 & 0xFFFFu), (float)(w1 >> 16));
            } else f = make_float4(0.f, 0.f, 0.f, 0.f);
            float4 m, spk;
            m.x = mem0.x * decay; m.x = m.x + f.x;
            m.y = mem0.y * decay; m.y = m.y + f.y;
            m.z = mem0.z * decay; m.z = m.z + f.z;
            m.w = mem0.w * decay; m.w = m.w + f.w;
            spk.x = (m.x >= thr) ? 1.0f : 0.0f;
            spk.y = (m.y >= thr) ? 1.0f : 0.0f;
            spk.z = (m.z >= thr) ? 1.0f : 0.0f;
            spk.w = (m.w >= thr) ? 1.0f : 0.0f;
            ((float4*)ob)[tid] = spk;
            mem0.x = m.x - spk.x * thr;
            mem0.y = m.y - spk.y * thr;
            mem0.z = m.z - spk.z * thr;
            mem0.w = m.w - spk.w * thr;
            cnt += (int)spk.x + (int)spk.y + (int)spk.z + (int)spk.w;
        }
        if (has1) {
            int g = tid + STHR;
            float4 f;
            if (s < T_EVT) {
                int w = s * 900 + (g << 1);
                unsigned w0 = lds_hist[w], w1 = lds_hist[w + 1];
                f = make_float4((float)(w0 & 0xFFFFu), (float)(w0 >> 16),
                                (float)(w1 & 0xFFFFu), (float)(w1 >> 16));
            } else f = make_float4(0.f, 0.f, 0.f, 0.f);
            float4 m, spk;
            m.x = mem1.x * decay; m.x = m.x + f.x;
            m.y = mem1.y * decay; m.y = m.y + f.y;
            m.z = mem1.z * decay; m.z = m.z + f.z;
            m.w = mem1.w * decay; m.w = m.w + f.w;
            spk.x = (m.x >= thr) ? 1.0f : 0.0f;
            spk.y = (m.y >= thr) ? 1.0f : 0.0f;
            spk.z = (m.z >= thr) ? 1.0f : 0.0f;
            spk.w = (m.w >= thr) ? 1.0f : 0.0f;
            ((float4*)ob)[g] = spk;
            mem1.x = m.x - spk.x * thr;
            mem1.y = m.y - spk.y * thr;
            mem1.z = m.z - spk.z * thr;
            mem1.w = m.w - spk.w * thr;
            cnt += (int)spk.x + (int)spk.y + (int)spk.z + (int)spk.w;
        }

        if (s == T_TOTAL - 1) break;

        for (int off = 32; off > 0; off >>= 1) cnt += __shfl_down(cnt, off, 64);
        unsigned total;
        if (lane == 0) {
            unsigned old = __hip_atomic_fetch_add(&lds_arr[s],
                               (unsigned)cnt + (1u << 16),
                               __ATOMIC_RELAXED, __HIP_MEMORY_SCOPE_WORKGROUP);
            if ((old >> 16) == SWPB - 1) {
                unsigned bc = (old + (unsigned)cnt) & 0xFFFFu;
                const int g1 = b >> 4;
                unsigned long long a1 = __hip_atomic_fetch_add(
                    &g_n1[s][g1][0], (unsigned long long)bc + ARRIVE64,
                    __ATOMIC_RELAXED, __HIP_MEMORY_SCOPE_AGENT);
                if ((unsigned)(a1 >> 32) == 15u) {
                    unsigned c1 = (unsigned)a1 + bc;
                    const int g2 = g1 >> 4;
                    unsigned long long a2 = __hip_atomic_fetch_add(
                        &g_n2[s][g2][0], (unsigned long long)c1 + ARRIVE64,
                        __ATOMIC_RELAXED, __HIP_MEMORY_SCOPE_AGENT);
                    if ((unsigned)(a2 >> 32) == 15u) {
                        unsigned c2 = (unsigned)a2 + c1;
                        unsigned long long a3 = __hip_atomic_fetch_add(
                            &g_n3[s][0], (unsigned long long)c2 + ARRIVE64,
                            __ATOMIC_RELAXED, __HIP_MEMORY_SCOPE_AGENT);
                        if ((unsigned)(a3 >> 32) == 3u) {
                            unsigned tot = (unsigned)a3 + c2;
                            for (int g = 0; g < 64; ++g)
                                __hip_atomic_store(&g_relg[s][g][0], tot + 1u,
                                    __ATOMIC_RELAXED, __HIP_MEMORY_SCOPE_AGENT);
                        }
                    }
                }
                unsigned f;
                do {
                    __builtin_amdgcn_s_sleep(1);
                    f = __hip_atomic_load(&g_relg[s][g1][0], __ATOMIC_RELAXED,
                                          __HIP_MEMORY_SCOPE_AGENT);
                } while (f == 0u);
                total = f - 1u;
                __hip_atomic_store(&lds_tot[s], f,
                                   __ATOMIC_RELAXED, __HIP_MEMORY_SCOPE_WORKGROUP);
            } else {
                unsigned f;
                do {
                    __builtin_amdgcn_s_sleep(1);
                    f = __hip_atomic_load(&lds_tot[s], __ATOMIC_RELAXED,
                                          __HIP_MEMORY_SCOPE_WORKGROUP);
                } while (f == 0u);
                total = f - 1u;
            }
        }
        total = (unsigned)__shfl((int)total, 0, 64);
        float rate = (float)total / 1843200.0f;
        thr = thr + 0.1f * (rate - 0.1f);
        thr = fminf(fmaxf(thr, 0.1f), 10.0f);
    }
}

// ======================= old (fallback) path =======================
__global__ void scatter_kernel(const int* __restrict__ x, const int* __restrict__ y,
                               const int* __restrict__ p, const float* __restrict__ t,
                               unsigned* __restrict__ hist32, int n) {
    int i = blockIdx.x * blockDim.x + threadIdx.x;
    if (i >= n) return;
    float tmin = key2f(g_minkey);
    float tmax = key2f(g_maxkey);
    int ti = event_bin_t(t[i], tmin, tmax);
    int pix = event_pixel(x[i], y[i], p[i]);
    size_t bidx = (size_t)ti * FRAME + pix;
    atomicAdd(hist32 + (bidx >> 1), 1u << ((bidx & 1) << 4));
}

__global__ __launch_bounds__(ONTHR) void scan_old(float* __restrict__ out) {
#pragma clang fp contract(off)
    const float decay = (float)0.9048374180359595;
    const int gtid = blockIdx.x * ONTHR + threadIdx.x;
    const int lane = threadIdx.x & 63;
    const uint2 uz2 = make_uint2(0u, 0u);
    float4 mem0 = make_float4(0.f, 0.f, 0.f, 0.f);
    float4 mem1 = make_float4(0.f, 0.f, 0.f, 0.f);
    const bool has1 = (gtid + ONT) < FRAME4;
    float thr = 1.0f;
    const uint2* hist2 = (const uint2*)(out + (size_t)T_EVT * FRAME);
    __shared__ unsigned lds_arr[T_TOTAL];
    __shared__ unsigned lds_tot[T_TOTAL];
    if (threadIdx.x < T_TOTAL) { lds_arr[threadIdx.x] = 0u; lds_tot[threadIdx.x] = 0u; }
    __syncthreads();
    uint2 u0 = hist2[gtid];
    uint2 u1 = has1 ? hist2[gtid + ONT] : uz2;
    for (int s = 0; s < T_TOTAL; ++s) {
        float4* o4 = (float4*)(out + (size_t)s * FRAME);
        int cnt = 0;
        {
            float4 m, spk;
            m.x = mem0.x * decay; m.x = m.x + (float)(u0.x & 0xFFFFu);
            m.y = mem0.y * decay; m.y = m.y + (float)(u0.x >> 16);
            m.z = mem0.z * decay; m.z = m.z + (float)(u0.y & 0xFFFFu);
            m.w = mem0.w * decay; m.w = m.w + (float)(u0.y >> 16);
            spk.x = (m.x >= thr) ? 1.0f : 0.0f;
            spk.y = (m.y >= thr) ? 1.0f : 0.0f;
            spk.z = (m.z >= thr) ? 1.0f : 0.0f;
            spk.w = (m.w >= thr) ? 1.0f : 0.0f;
            o4[gtid] = spk;
            mem0.x = m.x - spk.x * thr; mem0.y = m.y - spk.y * thr;
            mem0.z = m.z - spk.z * thr; mem0.w = m.w - spk.w * thr;
            cnt += (int)spk.x + (int)spk.y + (int)spk.z + (int)spk.w;
        }
        if (has1) {
            float4 m, spk;
            m.x = mem1.x * decay; m.x = m.x + (float)(u1.x & 0xFFFFu);
            m.y = mem1.y * decay; m.y = m.y + (float)(u1.x >> 16);
            m.z = mem1.z * decay; m.z = m.z + (float)(u1.y & 0xFFFFu);
            m.w = mem1.w * decay; m.w = m.w + (float)(u1.y >> 16);
            spk.x = (m.x >= thr) ? 1.0f : 0.0f;
            spk.y = (m.y >= thr) ? 1.0f : 0.0f;
            spk.z = (m.z >= thr) ? 1.0f : 0.0f;
            spk.w = (m.w >= thr) ? 1.0f : 0.0f;
            o4[gtid + ONT] = spk;
            mem1.x = m.x - spk.x * thr; mem1.y = m.y - spk.y * thr;
            mem1.z = m.z - spk.z * thr; mem1.w = m.w - spk.w * thr;
            cnt += (int)spk.x + (int)spk.y + (int)spk.z + (int)spk.w;
        }
        if (s + 1 < T_EVT) {
            const uint2* hn = hist2 + (size_t)(s + 1) * FRAME4;
            u0 = hn[gtid];
            u1 = has1 ? hn[gtid + ONT] : uz2;
        } else { u0 = uz2; u1 = uz2; }
        if (s == T_TOTAL - 1) break;
        for (int off = 32; off > 0; off >>= 1) cnt += __shfl_down(cnt, off, 64);
        unsigned total;
        if (lane == 0) {
            unsigned old = __hip_atomic_fetch_add(&lds_arr[s],
                               (unsigned)cnt + (1u << 16),
                               __ATOMIC_RELAXED, __HIP_MEMORY_SCOPE_WORKGROUP);
            if ((old >> 16) == ONWPB - 1) {
                unsigned bc = (old + (unsigned)cnt) & 0xFFFFu;
                const int gid = blockIdx.x >> 4;
                unsigned long long gold = __hip_atomic_fetch_add(
                    &g_grp[s][gid][0], (unsigned long long)bc + ARRIVE64,
                    __ATOMIC_RELAXED, __HIP_MEMORY_SCOPE_AGENT);
                if ((unsigned)(gold >> 32) == 15u) {
                    unsigned gc = (unsigned)gold + bc;
                    unsigned long long told = __hip_atomic_fetch_add(
                        &g_top[s][0], (unsigned long long)gc + ARRIVE64,
                        __ATOMIC_RELAXED, __HIP_MEMORY_SCOPE_AGENT);
                    if ((unsigned)(told >> 32) == 15u) {
                        unsigned tot = (unsigned)told + gc;
                        __hip_atomic_store(&g_rel[s][0], tot + 1u,
                                           __ATOMIC_RELAXED, __HIP_MEMORY_SCOPE_AGENT);
                    }
                }
                unsigned f;
                do {
                    __builtin_amdgcn_s_sleep(1);
                    f = __hip_atomic_load(&g_rel[s][0], __ATOMIC_RELAXED,
                                          __HIP_MEMORY_SCOPE_AGENT);
                } while (f == 0u);
                total = f - 1u;
                __hip_atomic_store(&lds_tot[s], f,
                                   __ATOMIC_RELAXED, __HIP_MEMORY_SCOPE_WORKGROUP);
            } else {
                unsigned f;
                do {
                    __builtin_amdgcn_s_sleep(1);
                    f = __hip_atomic_load(&lds_tot[s], __ATOMIC_RELAXED,
                                          __HIP_MEMORY_SCOPE_WORKGROUP);
                } while (f == 0u);
                total = f - 1u;
            }
        }
        total = (unsigned)__shfl((int)total, 0, 64);
        float rate = (float)total / 1843200.0f;
        thr = thr + 0.1f * (rate - 0.1f);
        thr = fminf(fmaxf(thr, 0.1f), 10.0f);
    }
}

extern "C" void kernel_launch(void* const* d_in, const int* in_sizes, int n_in,
                              void* d_out, int out_size, void* d_ws, size_t ws_size,
                              hipStream_t stream) {
    const int*   x = (const int*)d_in[0];
    const int*   y = (const int*)d_in[1];
    const int*   p = (const int*)d_in[2];
    const float* t = (const float*)d_in[3];
    float* out = (float*)d_out;
    const int n = in_sizes[0];

    init_kernel<<<64, 256, 0, stream>>>();

    if (d_ws != nullptr && ws_size >= WS_NEED(n)) {
        unsigned* mat = (unsigned*)((char*)d_ws + MAT_OFF);
        unsigned* colsum = (unsigned*)((char*)d_ws + CS_OFF);
        unsigned* seg_base = (unsigned*)((char*)d_ws + SB_OFF);
        unsigned* keys = (unsigned*)((char*)d_ws + KEY_OFF);
        unsigned short* seg = (unsigned short*)((char*)d_ws + SEG_OFF(n));

        passA_kernel<<<RBLK, RTHR, 0, stream>>>(x, y, p, t, mat, keys, n);
        offsets_kernel<<<NBUCKET, OTHR, 0, stream>>>(mat, colsum, seg_base);
        passB_kernel<<<RBLK, RTHR, 0, stream>>>(keys, t, mat, seg_base, seg, n);

        dim3 g(SBLK), b(STHR);
        void* args[] = { (void*)&out, (void*)&seg, (void*)&seg_base };
        hipLaunchCooperativeKernel((void*)scan_new, g, b, args, 0, stream);
    } else {
        unsigned* hist32 = (unsigned*)(out + (size_t)T_EVT * FRAME);
        minmax_zero_kernel<<<1024, 256, 0, stream>>>(t, n, (uint4*)hist32);
        scatter_kernel<<<(n + 255) / 256, 256, 0, stream>>>(x, y, p, t, hist32, n);
        dim3 g(ONBLK), b(ONTHR);
        void* args[] = { (void*)&out };
        hipLaunchCooperativeKernel((void*)scan_old, g, b, args, 0, stream);
    }
}

// Round 14
// 349.520 us; speedup vs baseline: 1.1313x; 1.1313x over previous
//
#include <hip/hip_runtime.h>
#include <cstddef>

#define HH 720
#define WW 1280
#define FRAME 1843200            // 2*720*1280
#define FRAME4 460800            // FRAME/4
#define T_EVT 10
#define T_TOTAL 20
#define ARRIVE64 (1ULL << 32)

// ---------- old (fallback) path config ----------
#define ONBLK 256
#define ONTHR 1024
#define ONWPB 16
#define ONT (ONBLK * ONTHR)

// ---------- new path config ----------
#define SBLK 1024                // scan blocks (4 per CU)
#define STHR 256                 // scan threads per block (4 waves)
#define SWPB 4
#define PIXB 1800                // pixels per scan block
#define NGROUP4 450              // float4 groups per block (1800/4)
#define HIST_W 9000              // LDS hist words (18000 u16)
#define RBLK 512                 // passA/passB blocks (x1024 thr = 32 waves/CU)
#define RTHR 1024
#define OTHR 512                 // offsets_col threads (one per mat row)
#define NBUCKET 1024

// ws layout (bytes), all 256-aligned
#define MAT_OFF   0u                           // u32[512*1024] = 2 MB
#define CS_OFF    (512u * 1024u * 4u)          // u32[1024] column sums
#define SB_OFF    (CS_OFF + 4096u)             // u32[1025] seg bases
#define KEY_OFF   (SB_OFF + 8192u)             // u32[n] pix keys
#define SEG_OFF(n) (KEY_OFF + 4u * (unsigned)(n))        // u16[n]
#define WS_NEED(n) ((size_t)SEG_OFF(n) + 2ull * (size_t)(n) + 256ull)

// Persistent device globals.
__device__ unsigned g_minkey;
__device__ unsigned g_maxkey;
// old-path tree (R8, proven)
__device__ unsigned long long g_grp[T_TOTAL][16][16];
__device__ unsigned long long g_top[T_TOTAL][16];
__device__ unsigned g_rel[T_TOTAL][32];
// new-path tree: 1024 -> 64 -> 4 -> 1, fan-out to 64 group-release words
__device__ unsigned long long g_n1[T_TOTAL][64][16];
__device__ unsigned long long g_n2[T_TOTAL][4][16];
__device__ unsigned long long g_n3[T_TOTAL][16];
__device__ unsigned g_relg[T_TOTAL][64][32];   // [s][group][0]: total+1

__device__ __forceinline__ unsigned f2key(float f) {
    unsigned b = __float_as_uint(f);
    return b ^ ((unsigned)(((int)b) >> 31) | 0x80000000u);
}
__device__ __forceinline__ float key2f(unsigned k) {
    unsigned b = (k & 0x80000000u) ? (k ^ 0x80000000u) : ~k;
    return __uint_as_float(b);
}

// Exact reference bin: ((t-tmin)/(tmax-tmin))*(10-1e-6), trunc, clip.
__device__ __forceinline__ int event_bin_t(float tv, float tmin, float tmax) {
#pragma clang fp contract(off)
    float tn;
    if (tmax > tmin) tn = (tv - tmin) / (tmax - tmin) * (float)(10.0 - 1e-6);
    else tn = 0.0f;
    int ti = (int)tn;
    return ti < 0 ? 0 : (ti > T_EVT - 1 ? T_EVT - 1 : ti);
}
__device__ __forceinline__ int event_pixel(int xi, int yi, int ci) {
    xi = xi < 0 ? 0 : (xi > WW - 1 ? WW - 1 : xi);
    yi = yi < 0 ? 0 : (yi > HH - 1 ? HH - 1 : yi);
    return ci * (HH * WW) + yi * WW + xi;
}

__global__ void init_kernel() {
    const int gtid = blockIdx.x * blockDim.x + threadIdx.x;
    const int gs = gridDim.x * blockDim.x;
    if (gtid == 0) { g_minkey = 0xFFFFFFFFu; g_maxkey = 0u; }
    unsigned long long* a = &g_grp[0][0][0];
    for (int i = gtid; i < T_TOTAL * 16 * 16; i += gs) a[i] = 0ull;
    unsigned long long* b = &g_top[0][0];
    for (int i = gtid; i < T_TOTAL * 16; i += gs) b[i] = 0ull;
    unsigned* c = &g_rel[0][0];
    for (int i = gtid; i < T_TOTAL * 32; i += gs) c[i] = 0u;
    unsigned long long* d = &g_n1[0][0][0];
    for (int i = gtid; i < T_TOTAL * 64 * 16; i += gs) d[i] = 0ull;
    unsigned long long* e = &g_n2[0][0][0];
    for (int i = gtid; i < T_TOTAL * 4 * 16; i += gs) e[i] = 0ull;
    unsigned long long* f = &g_n3[0][0];
    for (int i = gtid; i < T_TOTAL * 16; i += gs) f[i] = 0ull;
    unsigned* g = &g_relg[0][0][0];
    for (int i = gtid; i < T_TOTAL * 64 * 32; i += gs) g[i] = 0u;
}

// ======================= shared: t min/max =======================
__device__ __forceinline__ void minmax_body(const float* __restrict__ t, int n,
                                            int gtid, int gstride) {
    unsigned mn = 0xFFFFFFFFu, mx = 0u;
    const int n4 = n >> 2;
    const float4* t4 = (const float4*)t;
    for (int i = gtid; i < n4; i += gstride) {
        float4 tv = t4[i];
        unsigned k0 = f2key(tv.x), k1 = f2key(tv.y);
        unsigned k2 = f2key(tv.z), k3 = f2key(tv.w);
        unsigned a = k0 < k1 ? k0 : k1, b = k2 < k3 ? k2 : k3;
        unsigned c = a < b ? a : b;
        mn = mn < c ? mn : c;
        a = k0 > k1 ? k0 : k1; b = k2 > k3 ? k2 : k3;
        c = a > b ? a : b;
        mx = mx > c ? mx : c;
    }
    for (int i = (n4 << 2) + gtid; i < n; i += gstride) {
        unsigned k = f2key(t[i]);
        mn = mn < k ? mn : k;
        mx = mx > k ? mx : k;
    }
    for (int off = 32; off > 0; off >>= 1) {
        unsigned omn = (unsigned)__shfl_down((int)mn, off, 64);
        unsigned omx = (unsigned)__shfl_down((int)mx, off, 64);
        mn = mn < omn ? mn : omn;
        mx = mx > omx ? mx : omx;
    }
    __shared__ unsigned smn[16], smx[16];
    int lane = threadIdx.x & 63, wv = threadIdx.x >> 6;
    if (lane == 0) { smn[wv] = mn; smx[wv] = mx; }
    __syncthreads();
    if (threadIdx.x == 0) {
        int nw = blockDim.x >> 6;
        for (int i = 1; i < nw; ++i) {
            mn = mn < smn[i] ? mn : smn[i];
            mx = mx > smx[i] ? mx : smx[i];
        }
        atomicMin(&g_minkey, mn);
        atomicMax(&g_maxkey, mx);
    }
}

__global__ void minmax_zero_kernel(const float* __restrict__ t, int n,
                                   uint4* __restrict__ hist16v) {
    const int gtid = blockIdx.x * blockDim.x + threadIdx.x;
    const int gstride = gridDim.x * blockDim.x;
    const uint4 z = make_uint4(0u, 0u, 0u, 0u);
    const int nz = T_EVT * FRAME / 8;
    for (int i = gtid; i < nz; i += gstride) hist16v[i] = z;
    minmax_body(t, n, gtid, gstride);
}

// ======================= new path: counting sort =======================
// passA: events read ONCE -> pix keys (u32, 16 MB) + LDS bucket counts + t
// minmax fused (independent work, one kernel).
__global__ __launch_bounds__(RTHR) void passA_kernel(
        const int* __restrict__ x, const int* __restrict__ y,
        const int* __restrict__ p, const float* __restrict__ t,
        unsigned* __restrict__ mat, unsigned* __restrict__ keys, int n) {
    __shared__ unsigned cnt[NBUCKET];
    for (int i = threadIdx.x; i < NBUCKET; i += blockDim.x) cnt[i] = 0u;
    __syncthreads();
    const int chunk = (n + (int)gridDim.x - 1) / (int)gridDim.x;
    const int s0 = blockIdx.x * chunk;
    const int s1 = min(n, s0 + chunk);
    for (int i = s0 + threadIdx.x; i < s1; i += blockDim.x) {
        int pix = event_pixel(x[i], y[i], p[i]);
        keys[i] = (unsigned)pix;
        atomicAdd(&cnt[pix / PIXB], 1u);
    }
    minmax_body(t, n, blockIdx.x * blockDim.x + threadIdx.x,
                gridDim.x * blockDim.x);
    __syncthreads();
    for (int i = threadIdx.x; i < NBUCKET; i += blockDim.x)
        mat[blockIdx.x * NBUCKET + i] = cnt[i];
}

// offsets_col: one block per bucket column, exclusive scan of 512 row counts.
// NO arrival counter / threadfence — the kernel boundary is the sync (the
// R12/R13 fused version's 1024 same-line RMWs on g_done cost ~34 us, per R5's
// ~33 ns/same-line-op calibration).
__global__ __launch_bounds__(OTHR) void offsets_col_kernel(
        unsigned* __restrict__ mat, unsigned* __restrict__ colsum) {
    const int j = blockIdx.x;        // bucket
    const int r = threadIdx.x;       // row, 0..511
    const int lane = r & 63, wv = r >> 6;
    unsigned v = mat[r * NBUCKET + j];
    unsigned incl = v;
    for (int off = 1; off < 64; off <<= 1) {
        unsigned o = (unsigned)__shfl_up((int)incl, off, 64);
        if (lane >= off) incl += o;
    }
    __shared__ unsigned wtot[OTHR / 64];
    if (lane == 63) wtot[wv] = incl;
    __syncthreads();
    if (r == 0) {
        unsigned run = 0;
#pragma unroll
        for (int k = 0; k < OTHR / 64; ++k) { unsigned tmp = wtot[k]; wtot[k] = run; run += tmp; }
    }
    __syncthreads();
    unsigned ex = incl - v + wtot[wv];
    mat[r * NBUCKET + j] = ex;
    if (r == OTHR - 1) colsum[j] = ex + v;
}

// passB: prologue redundantly block-scans colsum (1024 = blockDim, one elem
// per thread; 4 KB L2-hit read per block) -> seg_base in LDS; block 0 also
// stores it to global for scan_new (kernel boundary = visibility). Then
// keys (16 MB) + t (16 MB) -> LDS rank -> u16 seg.
__global__ __launch_bounds__(RTHR) void passB_kernel(
        const unsigned* __restrict__ keys, const float* __restrict__ t,
        const unsigned* __restrict__ mat, const unsigned* __restrict__ colsum,
        unsigned* __restrict__ seg_base_out,
        unsigned short* __restrict__ seg, int n) {
    __shared__ unsigned base[NBUCKET];
    __shared__ unsigned wt2[RTHR / 64];
    {
        const int j = threadIdx.x;   // RTHR == NBUCKET
        const int lane = j & 63, wv = j >> 6;
        unsigned v = colsum[j];
        unsigned incl = v;
        for (int off = 1; off < 64; off <<= 1) {
            unsigned o = (unsigned)__shfl_up((int)incl, off, 64);
            if (lane >= off) incl += o;
        }
        if (lane == 63) wt2[wv] = incl;
        __syncthreads();
        if (j == 0) {
            unsigned run = 0;
#pragma unroll
            for (int k = 0; k < RTHR / 64; ++k) { unsigned tmp = wt2[k]; wt2[k] = run; run += tmp; }
        }
        __syncthreads();
        unsigned ex = incl - v + wt2[wv];
        base[j] = mat[blockIdx.x * NBUCKET + j] + ex;
        if (blockIdx.x == 0) {
            seg_base_out[j] = ex;
            if (j == NBUCKET - 1) seg_base_out[NBUCKET] = ex + v;
        }
    }
    __syncthreads();
    const float tmin = key2f(g_minkey);
    const float tmax = key2f(g_maxkey);
    const int chunk = (n + (int)gridDim.x - 1) / (int)gridDim.x;
    const int s0 = blockIdx.x * chunk;
    const int s1 = min(n, s0 + chunk);
    for (int i = s0 + threadIdx.x; i < s1; i += blockDim.x) {
        int pix = (int)keys[i];
        int ti = event_bin_t(t[i], tmin, tmax);
        int bkt = pix / PIXB;
        int lb = ti * PIXB + (pix - bkt * PIXB);   // < 18000
        unsigned idx = atomicAdd(&base[bkt], 1u);
        seg[idx] = (unsigned short)lb;
    }
}

// Cooperative scan, 1024 blocks x 256 thr, 36 KB LDS hist (R9-R13, proven).
__global__ __launch_bounds__(STHR, 4) void scan_new(float* __restrict__ out,
                                                    const unsigned short* __restrict__ seg,
                                                    const unsigned* __restrict__ seg_base) {
#pragma clang fp contract(off)
    const float decay = (float)0.9048374180359595;  // float32(exp(-1/10))
    const int tid = threadIdx.x;
    const int lane = tid & 63;
    const int b = blockIdx.x;
    const int pix0 = b * PIXB;

    __shared__ unsigned lds_hist[HIST_W];
    __shared__ unsigned lds_arr[T_TOTAL];
    __shared__ unsigned lds_tot[T_TOTAL];

    for (int i = tid; i < HIST_W; i += STHR) lds_hist[i] = 0u;
    if (tid < T_TOTAL) { lds_arr[tid] = 0u; lds_tot[tid] = 0u; }
    __syncthreads();

    {
        const int e0 = (int)seg_base[b];
        const int e1 = (int)seg_base[b + 1];
        for (int i = e0 + tid; i < e1; i += STHR) {
            unsigned lb = seg[i];
            atomicAdd(&lds_hist[lb >> 1], 1u << ((lb & 1u) << 4));
        }
    }
    __syncthreads();

    const bool has1 = tid < (NGROUP4 - STHR);
    float4 mem0 = make_float4(0.f, 0.f, 0.f, 0.f);
    float4 mem1 = make_float4(0.f, 0.f, 0.f, 0.f);
    float thr = 1.0f;

    for (int s = 0; s < T_TOTAL; ++s) {
        float* ob = out + (size_t)s * FRAME + pix0;
        int cnt = 0;

        {
            float4 f;
            if (s < T_EVT) {
                int w = s * 900 + (tid << 1);
                unsigned w0 = lds_hist[w], w1 = lds_hist[w + 1];
                f = make_float4((float)(w0 & 0xFFFFu), (float)(w0 >> 16),
                                (float)(w1 & 0xFFFFu), (float)(w1 >> 16));
            } else f = make_float4(0.f, 0.f, 0.f, 0.f);
            float4 m, spk;
            m.x = mem0.x * decay; m.x = m.x + f.x;
            m.y = mem0.y * decay; m.y = m.y + f.y;
            m.z = mem0.z * decay; m.z = m.z + f.z;
            m.w = mem0.w * decay; m.w = m.w + f.w;
            spk.x = (m.x >= thr) ? 1.0f : 0.0f;
            spk.y = (m.y >= thr) ? 1.0f : 0.0f;
            spk.z = (m.z >= thr) ? 1.0f : 0.0f;
            spk.w = (m.w >= thr) ? 1.0f : 0.0f;
            ((float4*)ob)[tid] = spk;
            mem0.x = m.x - spk.x * thr;
            mem0.y = m.y - spk.y * thr;
            mem0.z = m.z - spk.z * thr;
            mem0.w = m.w - spk.w * thr;
            cnt += (int)spk.x + (int)spk.y + (int)spk.z + (int)spk.w;
        }
        if (has1) {
            int g = tid + STHR;
            float4 f;
            if (s < T_EVT) {
                int w = s * 900 + (g << 1);
                unsigned w0 = lds_hist[w], w1 = lds_hist[w + 1];
                f = make_float4((float)(w0 & 0xFFFFu), (float)(w0 >> 16),
                                (float)(w1 & 0xFFFFu), (float)(w1 >> 16));
            } else f = make_float4(0.f, 0.f, 0.f, 0.f);
            float4 m, spk;
            m.x = mem1.x * decay; m.x = m.x + f.x;
            m.y = mem1.y * decay; m.y = m.y + f.y;
            m.z = mem1.z * decay; m.z = m.z + f.z;
            m.w = mem1.w * decay; m.w = m.w + f.w;
            spk.x = (m.x >= thr) ? 1.0f : 0.0f;
            spk.y = (m.y >= thr) ? 1.0f : 0.0f;
            spk.z = (m.z >= thr) ? 1.0f : 0.0f;
            spk.w = (m.w >= thr) ? 1.0f : 0.0f;
            ((float4*)ob)[g] = spk;
            mem1.x = m.x - spk.x * thr;
            mem1.y = m.y - spk.y * thr;
            mem1.z = m.z - spk.z * thr;
            mem1.w = m.w - spk.w * thr;
            cnt += (int)spk.x + (int)spk.y + (int)spk.z + (int)spk.w;
        }

        if (s == T_TOTAL - 1) break;

        for (int off = 32; off > 0; off >>= 1) cnt += __shfl_down(cnt, off, 64);
        unsigned total;
        if (lane == 0) {
            unsigned old = __hip_atomic_fetch_add(&lds_arr[s],
                               (unsigned)cnt + (1u << 16),
                               __ATOMIC_RELAXED, __HIP_MEMORY_SCOPE_WORKGROUP);
            if ((old >> 16) == SWPB - 1) {
                unsigned bc = (old + (unsigned)cnt) & 0xFFFFu;
                const int g1 = b >> 4;
                unsigned long long a1 = __hip_atomic_fetch_add(
                    &g_n1[s][g1][0], (unsigned long long)bc + ARRIVE64,
                    __ATOMIC_RELAXED, __HIP_MEMORY_SCOPE_AGENT);
                if ((unsigned)(a1 >> 32) == 15u) {
                    unsigned c1 = (unsigned)a1 + bc;
                    const int g2 = g1 >> 4;
                    unsigned long long a2 = __hip_atomic_fetch_add(
                        &g_n2[s][g2][0], (unsigned long long)c1 + ARRIVE64,
                        __ATOMIC_RELAXED, __HIP_MEMORY_SCOPE_AGENT);
                    if ((unsigned)(a2 >> 32) == 15u) {
                        unsigned c2 = (unsigned)a2 + c1;
                        unsigned long long a3 = __hip_atomic_fetch_add(
                            &g_n3[s][0], (unsigned long long)c2 + ARRIVE64,
                            __ATOMIC_RELAXED, __HIP_MEMORY_SCOPE_AGENT);
                        if ((unsigned)(a3 >> 32) == 3u) {
                            unsigned tot = (unsigned)a3 + c2;
                            for (int g = 0; g < 64; ++g)
                                __hip_atomic_store(&g_relg[s][g][0], tot + 1u,
                                    __ATOMIC_RELAXED, __HIP_MEMORY_SCOPE_AGENT);
                        }
                    }
                }
                unsigned f;
                do {
                    __builtin_amdgcn_s_sleep(1);
                    f = __hip_atomic_load(&g_relg[s][g1][0], __ATOMIC_RELAXED,
                                          __HIP_MEMORY_SCOPE_AGENT);
                } while (f == 0u);
                total = f - 1u;
                __hip_atomic_store(&lds_tot[s], f,
                                   __ATOMIC_RELAXED, __HIP_MEMORY_SCOPE_WORKGROUP);
            } else {
                unsigned f;
                do {
                    __builtin_amdgcn_s_sleep(1);
                    f = __hip_atomic_load(&lds_tot[s], __ATOMIC_RELAXED,
                                          __HIP_MEMORY_SCOPE_WORKGROUP);
                } while (f == 0u);
                total = f - 1u;
            }
        }
        total = (unsigned)__shfl((int)total, 0, 64);
        float rate = (float)total / 1843200.0f;
        thr = thr + 0.1f * (rate - 0.1f);
        thr = fminf(fmaxf(thr, 0.1f), 10.0f);
    }
}

// ======================= old (fallback) path =======================
__global__ void scatter_kernel(const int* __restrict__ x, const int* __restrict__ y,
                               const int* __restrict__ p, const float* __restrict__ t,
                               unsigned* __restrict__ hist32, int n) {
    int i = blockIdx.x * blockDim.x + threadIdx.x;
    if (i >= n) return;
    float tmin = key2f(g_minkey);
    float tmax = key2f(g_maxkey);
    int ti = event_bin_t(t[i], tmin, tmax);
    int pix = event_pixel(x[i], y[i], p[i]);
    size_t bidx = (size_t)ti * FRAME + pix;
    atomicAdd(hist32 + (bidx >> 1), 1u << ((bidx & 1) << 4));
}

__global__ __launch_bounds__(ONTHR) void scan_old(float* __restrict__ out) {
#pragma clang fp contract(off)
    const float decay = (float)0.9048374180359595;
    const int gtid = blockIdx.x * ONTHR + threadIdx.x;
    const int lane = threadIdx.x & 63;
    const uint2 uz2 = make_uint2(0u, 0u);
    float4 mem0 = make_float4(0.f, 0.f, 0.f, 0.f);
    float4 mem1 = make_float4(0.f, 0.f, 0.f, 0.f);
    const bool has1 = (gtid + ONT) < FRAME4;
    float thr = 1.0f;
    const uint2* hist2 = (const uint2*)(out + (size_t)T_EVT * FRAME);
    __shared__ unsigned lds_arr[T_TOTAL];
    __shared__ unsigned lds_tot[T_TOTAL];
    if (threadIdx.x < T_TOTAL) { lds_arr[threadIdx.x] = 0u; lds_tot[threadIdx.x] = 0u; }
    __syncthreads();
    uint2 u0 = hist2[gtid];
    uint2 u1 = has1 ? hist2[gtid + ONT] : uz2;
    for (int s = 0; s < T_TOTAL; ++s) {
        float4* o4 = (float4*)(out + (size_t)s * FRAME);
        int cnt = 0;
        {
            float4 m, spk;
            m.x = mem0.x * decay; m.x = m.x + (float)(u0.x & 0xFFFFu);
            m.y = mem0.y * decay; m.y = m.y + (float)(u0.x >> 16);
            m.z = mem0.z * decay; m.z = m.z + (float)(u0.y & 0xFFFFu);
            m.w = mem0.w * decay; m.w = m.w + (float)(u0.y >> 16);
            spk.x = (m.x >= thr) ? 1.0f : 0.0f;
            spk.y = (m.y >= thr) ? 1.0f : 0.0f;
            spk.z = (m.z >= thr) ? 1.0f : 0.0f;
            spk.w = (m.w >= thr) ? 1.0f : 0.0f;
            o4[gtid] = spk;
            mem0.x = m.x - spk.x * thr; mem0.y = m.y - spk.y * thr;
            mem0.z = m.z - spk.z * thr; mem0.w = m.w - spk.w * thr;
            cnt += (int)spk.x + (int)spk.y + (int)spk.z + (int)spk.w;
        }
        if (has1) {
            float4 m, spk;
            m.x = mem1.x * decay; m.x = m.x + (float)(u1.x & 0xFFFFu);
            m.y = mem1.y * decay; m.y = m.y + (float)(u1.x >> 16);
            m.z = mem1.z * decay; m.z = m.z + (float)(u1.y & 0xFFFFu);
            m.w = mem1.w * decay; m.w = m.w + (float)(u1.y >> 16);
            spk.x = (m.x >= thr) ? 1.0f : 0.0f;
            spk.y = (m.y >= thr) ? 1.0f : 0.0f;
            spk.z = (m.z >= thr) ? 1.0f : 0.0f;
            spk.w = (m.w >= thr) ? 1.0f : 0.0f;
            o4[gtid + ONT] = spk;
            mem1.x = m.x - spk.x * thr; mem1.y = m.y - spk.y * thr;
            mem1.z = m.z - spk.z * thr; mem1.w = m.w - spk.w * thr;
            cnt += (int)spk.x + (int)spk.y + (int)spk.z + (int)spk.w;
        }
        if (s + 1 < T_EVT) {
            const uint2* hn = hist2 + (size_t)(s + 1) * FRAME4;
            u0 = hn[gtid];
            u1 = has1 ? hn[gtid + ONT] : uz2;
        } else { u0 = uz2; u1 = uz2; }
        if (s == T_TOTAL - 1) break;
        for (int off = 32; off > 0; off >>= 1) cnt += __shfl_down(cnt, off, 64);
        unsigned total;
        if (lane == 0) {
            unsigned old = __hip_atomic_fetch_add(&lds_arr[s],
                               (unsigned)cnt + (1u << 16),
                               __ATOMIC_RELAXED, __HIP_MEMORY_SCOPE_WORKGROUP);
            if ((old >> 16) == ONWPB - 1) {
                unsigned bc = (old + (unsigned)cnt) & 0xFFFFu;
                const int gid = blockIdx.x >> 4;
                unsigned long long gold = __hip_atomic_fetch_add(
                    &g_grp[s][gid][0], (unsigned long long)bc + ARRIVE64,
                    __ATOMIC_RELAXED, __HIP_MEMORY_SCOPE_AGENT);
                if ((unsigned)(gold >> 32) == 15u) {
                    unsigned gc = (unsigned)gold + bc;
                    unsigned long long told = __hip_atomic_fetch_add(
                        &g_top[s][0], (unsigned long long)gc + ARRIVE64,
                        __ATOMIC_RELAXED, __HIP_MEMORY_SCOPE_AGENT);
                    if ((unsigned)(told >> 32) == 15u) {
                        unsigned tot = (unsigned)told + gc;
                        __hip_atomic_store(&g_rel[s][0], tot + 1u,
                                           __ATOMIC_RELAXED, __HIP_MEMORY_SCOPE_AGENT);
                    }
                }
                unsigned f;
                do {
                    __builtin_amdgcn_s_sleep(1);
                    f = __hip_atomic_load(&g_rel[s][0], __ATOMIC_RELAXED,
                                          __HIP_MEMORY_SCOPE_AGENT);
                } while (f == 0u);
                total = f - 1u;
                __hip_atomic_store(&lds_tot[s], f,
                                   __ATOMIC_RELAXED, __HIP_MEMORY_SCOPE_WORKGROUP);
            } else {
                unsigned f;
                do {
                    __builtin_amdgcn_s_sleep(1);
                    f = __hip_atomic_load(&lds_tot[s], __ATOMIC_RELAXED,
                                          __HIP_MEMORY_SCOPE_WORKGROUP);
                } while (f == 0u);
                total = f - 1u;
            }
        }
        total = (unsigned)__shfl((int)total, 0, 64);
        float rate = (float)total / 1843200.0f;
        thr = thr + 0.1f * (rate - 0.1f);
        thr = fminf(fmaxf(thr, 0.1f), 10.0f);
    }
}

extern "C" void kernel_launch(void* const* d_in, const int* in_sizes, int n_in,
                              void* d_out, int out_size, void* d_ws, size_t ws_size,
                              hipStream_t stream) {
    const int*   x = (const int*)d_in[0];
    const int*   y = (const int*)d_in[1];
    const int*   p = (const int*)d_in[2];
    const float* t = (const float*)d_in[3];
    float* out = (float*)d_out;
    const int n = in_sizes[0];

    init_kernel<<<64, 256, 0, stream>>>();

    if (d_ws != nullptr && ws_size >= WS_NEED(n)) {
        unsigned* mat = (unsigned*)((char*)d_ws + MAT_OFF);
        unsigned* colsum = (unsigned*)((char*)d_ws + CS_OFF);
        unsigned* seg_base = (unsigned*)((char*)d_ws + SB_OFF);
        unsigned* keys = (unsigned*)((char*)d_ws + KEY_OFF);
        unsigned short* seg = (unsigned short*)((char*)d_ws + SEG_OFF(n));

        passA_kernel<<<RBLK, RTHR, 0, stream>>>(x, y, p, t, mat, keys, n);
        offsets_col_kernel<<<NBUCKET, OTHR, 0, stream>>>(mat, colsum);
        passB_kernel<<<RBLK, RTHR, 0, stream>>>(keys, t, mat, colsum, seg_base, seg, n);

        dim3 g(SBLK), b(STHR);
        void* args[] = { (void*)&out, (void*)&seg, (void*)&seg_base };
        hipLaunchCooperativeKernel((void*)scan_new, g, b, args, 0, stream);
    } else {
        unsigned* hist32 = (unsigned*)(out + (size_t)T_EVT * FRAME);
        minmax_zero_kernel<<<1024, 256, 0, stream>>>(t, n, (uint4*)hist32);
        scatter_kernel<<<(n + 255) / 256, 256, 0, stream>>>(x, y, p, t, hist32, n);
        dim3 g(ONBLK), b(ONTHR);
        void* args[] = { (void*)&out };
        hipLaunchCooperativeKernel((void*)scan_old, g, b, args, 0, stream);
    }
}